// Round 5
// baseline (4830.044 us; speedup 1.0000x reference)
//
#include <hip/hip_runtime.h>
#include <float.h>

#define KC 4096
#define DIM 256
#define MB 16384            // m per batch element (16*32*32)
#define NTOT 65536          // 4 * MB rows
#define ZELEMS 16777216     // 4 * 256 * 16384  (z_q_st element count)
#define LOSS_OFF 16777216
#define IDX_OFF  16777217

// Replicates the np float32 reference: dist = (A - 2G) + B evaluated in f32,
// where A=|z_row|^2 (f32), G=z.e (f32 from fp64 accum), B=|e_k|^2 (f32).
// Since B < ULP(A-2G)/2 it is absorbed; scores are effectively fl32(A-2G),
// heavily tied -> np.argmin first-index tie-break replicated exactly.
__global__ __launch_bounds__(256) void vq_main(const float* __restrict__ z,
                                               const float* __restrict__ e,
                                               float* __restrict__ out) {
    __shared__ float lds_e[32][DIM + 4];
    __shared__ float lds_bs[4][64];
    __shared__ int lds_bi[4][64];
    __shared__ int lds_fi[64];
    __shared__ double lds_ls[4];

    const int tid = threadIdx.x;
    const int wave = tid >> 6, lane = tid & 63;
    const int l16 = lane & 15, g = lane >> 4;
    const int nbase = blockIdx.x * 64;
    const int b = nbase / MB;
    const int mbase = nbase % MB;
    const float* zb = z + (size_t)b * DIM * MB;   // z[b][d][m]
    const int mrow = mbase + 4 * l16;             // this lane's 4 rows
    const int cw = wave * 8 + g * 2;              // code offset within chunk

    // Per-row A = |z_row|^2 (fp64 accumulate -> f32). Low bits of A are
    // argmin-irrelevant (uniform grid shift), so exact np summation order
    // is not needed.
    double sA[4] = {0.0, 0.0, 0.0, 0.0};
    for (int d = 0; d < DIM; ++d) {
        float4 zv = *reinterpret_cast<const float4*>(zb + (size_t)d * MB + mrow);
        sA[0] = fma((double)zv.x, (double)zv.x, sA[0]);
        sA[1] = fma((double)zv.y, (double)zv.y, sA[1]);
        sA[2] = fma((double)zv.z, (double)zv.z, sA[2]);
        sA[3] = fma((double)zv.w, (double)zv.w, sA[3]);
    }
    float Af[4];
    #pragma unroll
    for (int i = 0; i < 4; ++i) Af[i] = (float)sA[i];

    float bs[4];
    int bi[4];
    #pragma unroll
    for (int i = 0; i < 4; ++i) { bs[i] = FLT_MAX; bi[i] = 0; }

    for (int chunk = 0; chunk < KC / 32; ++chunk) {
        const int cbase = chunk * 32;
        // stage 32 codes x 256 dims into LDS (coalesced float4)
        {
            const float4* src = reinterpret_cast<const float4*>(e + (size_t)cbase * DIM);
            #pragma unroll
            for (int i = 0; i < 8; ++i) {
                int f = tid + 256 * i;
                int code = f >> 6;
                int d4 = f & 63;
                *reinterpret_cast<float4*>(&lds_e[code][d4 * 4]) = src[f];
            }
        }
        __syncthreads();

        // |e|^2 for this lane's 2 codes (fp64, cooperative across the 16
        // lanes sharing them), then to f32. (B is argmin-irrelevant but kept
        // for formula fidelity.)
        double cs0 = 0.0, cs1 = 0.0;
        #pragma unroll
        for (int dd = 0; dd < 16; ++dd) {
            float a0 = lds_e[cw][l16 * 16 + dd];
            float a1 = lds_e[cw + 1][l16 * 16 + dd];
            cs0 += (double)a0 * a0;
            cs1 += (double)a1 * a1;
        }
        #pragma unroll
        for (int m = 1; m < 16; m <<= 1) {
            cs0 += __shfl_xor(cs0, m);
            cs1 += __shfl_xor(cs1, m);
        }
        const float bf0 = (float)cs0, bf1 = (float)cs1;

        double acc[4][2];
        #pragma unroll
        for (int i = 0; i < 4; ++i) { acc[i][0] = 0.0; acc[i][1] = 0.0; }

        for (int d = 0; d < DIM; ++d) {
            float4 zv = *reinterpret_cast<const float4*>(zb + (size_t)d * MB + mrow);
            double e0 = (double)lds_e[cw][d];
            double e1 = (double)lds_e[cw + 1][d];
            acc[0][0] = fma((double)zv.x, e0, acc[0][0]);
            acc[1][0] = fma((double)zv.y, e0, acc[1][0]);
            acc[2][0] = fma((double)zv.z, e0, acc[2][0]);
            acc[3][0] = fma((double)zv.w, e0, acc[3][0]);
            acc[0][1] = fma((double)zv.x, e1, acc[0][1]);
            acc[1][1] = fma((double)zv.y, e1, acc[1][1]);
            acc[2][1] = fma((double)zv.z, e1, acc[2][1]);
            acc[3][1] = fma((double)zv.w, e1, acc[3][1]);
        }

        const int k0 = cbase + cw;
        #pragma unroll
        for (int i = 0; i < 4; ++i) {
            // f32 replica of np: ((A - 2G) + B), two separate f32 adds
            float g0 = (float)(2.0 * acc[i][0]);
            float g1 = (float)(2.0 * acc[i][1]);
            float t0 = Af[i] - g0;
            float t1 = Af[i] - g1;
            float s0 = t0 + bf0;
            float s1 = t1 + bf1;
            // ascending k within lane -> strict < keeps earliest (np tie rule)
            if (s0 < bs[i]) { bs[i] = s0; bi[i] = k0; }
            if (s1 < bs[i]) { bs[i] = s1; bi[i] = k0 + 1; }
        }
        __syncthreads();
    }

    // combine across g-groups (lanes l16, l16+16, l16+32, l16+48 share rows)
    #pragma unroll
    for (int off = 16; off < 64; off <<= 1) {
        #pragma unroll
        for (int i = 0; i < 4; ++i) {
            float os = __shfl_xor(bs[i], off);
            int oi = __shfl_xor(bi[i], off);
            if (os < bs[i] || (os == bs[i] && oi < bi[i])) { bs[i] = os; bi[i] = oi; }
        }
    }
    if (g == 0) {
        #pragma unroll
        for (int i = 0; i < 4; ++i) {
            lds_bs[wave][4 * l16 + i] = bs[i];
            lds_bi[wave][4 * l16 + i] = bi[i];
        }
    }
    __syncthreads();
    if (tid < 64) {
        float best = lds_bs[0][tid];
        int idx = lds_bi[0][tid];
        #pragma unroll
        for (int wv = 1; wv < 4; ++wv) {
            float os = lds_bs[wv][tid];
            int oi = lds_bi[wv][tid];
            if (os < best || (os == best && oi < idx)) { best = os; idx = oi; }
        }
        lds_fi[tid] = idx;
        out[IDX_OFF + nbase + tid] = (float)idx;
    }
    __syncthreads();

    // z_q scatter (coalesced per-d-plane) + fused vq_loss partial
    double lsum = 0.0;
    const int mloc = tid & 63;
    const int d0 = tid >> 6;
    const int code = lds_fi[mloc];
    const float* erow = e + (size_t)code * DIM;
    #pragma unroll 4
    for (int d = d0; d < DIM; d += 4) {
        float ev = erow[d];
        size_t off = (size_t)b * (DIM * MB) + (size_t)d * MB + mbase + mloc;
        float zv = z[off];
        out[off] = ev;
        float diff = ev - zv;
        lsum += (double)diff * diff;
    }
    #pragma unroll
    for (int off = 32; off > 0; off >>= 1) lsum += __shfl_down(lsum, off);
    if (lane == 0) lds_ls[wave] = lsum;
    __syncthreads();
    if (tid == 0) {
        double t = lds_ls[0] + lds_ls[1] + lds_ls[2] + lds_ls[3];
        atomicAdd(out + LOSS_OFF, (float)(t * (1.25 / (double)ZELEMS)));
    }
}

extern "C" void kernel_launch(void* const* d_in, const int* in_sizes, int n_in,
                              void* d_out, int out_size, void* d_ws, size_t ws_size,
                              hipStream_t stream) {
    const float* z = (const float*)d_in[0];    // [4,256,16,32,32] fp32
    const float* e = (const float*)d_in[1];    // [4096,256] fp32
    float* out = (float*)d_out;

    // loss slot accumulates via atomicAdd -> must be zeroed every call
    hipMemsetAsync(out + LOSS_OFF, 0, sizeof(float), stream);
    vq_main<<<NTOT / 64, 256, 0, stream>>>(z, e, out);
}